// Round 1
// baseline (234.513 us; speedup 1.0000x reference)
//
#include <hip/hip_runtime.h>

#define B_  512
#define T_  365
#define C_  10
#define P_  64
#define K_  3650   // T*C
#define K2_ 1825   // K_/2 as float2

// d_out flat offsets (floats), in reference return order
#define OFF_OUT0 0u          // output_seq [B,T,C]
#define OFF_IN   1868800u    // input_seq  [B,T,C]
#define OFF_DIST 3737600u    // distances  [B,P]
#define OFF_IDX  3770368u    // indices    [B]
#define OFF_LAB  3770880u    // label      [B]
#define OFF_MASK 3771392u    // mask       [B,T]

// sp[p*T_+t] = sum_c proto[p,t,c]^2
__global__ void sp_kernel(const float* __restrict__ protos, float* __restrict__ sp) {
    int i = blockIdx.x * 256 + threadIdx.x;
    if (i >= P_ * T_) return;
    const float* p = protos + (size_t)i * C_;
    float s = 0.f;
#pragma unroll
    for (int c = 0; c < C_; ++c) s = fmaf(p[c], p[c], s);
    sp[i] = s;
}

__global__ __launch_bounds__(256) void dist_kernel(
    const float* __restrict__ x, const float* __restrict__ mask,
    const int* __restrict__ label, const float* __restrict__ protos,
    const float* __restrict__ sp, float* __restrict__ out)
{
    __shared__ float xm[2][3652];   // masked x rows, padded to even f2 count
    __shared__ float mrow[2][368];  // mask rows
    __shared__ float dist[2][64];
    __shared__ float x2s[2];
    __shared__ float wsum[4][2];
    __shared__ int   sel[2];

    const int tid  = threadIdx.x;
    const int lane = tid & 63;
    const int wv   = tid >> 6;
    const int b0   = blockIdx.x * 2;

    // ---- stage masked x rows + mask rows into LDS, accumulate x2m partials ----
    float s2[2] = {0.f, 0.f};
#pragma unroll
    for (int bb = 0; bb < 2; ++bb) {
        const int b = b0 + bb;
        const float* xb = x + (size_t)b * K_;
        const float* mb = mask + (size_t)b * T_;
        for (int i = tid; i < 3652; i += 256) {
            float v = 0.f;
            if (i < K_) v = xb[i] * mb[i / C_];
            xm[bb][i] = v;
            s2[bb] = fmaf(v, v, s2[bb]);   // m in {0,1} -> (m x)^2 = m x^2
        }
        for (int t = tid; t < T_; t += 256) mrow[bb][t] = mb[t];
    }
#pragma unroll
    for (int bb = 0; bb < 2; ++bb) {
        float v = s2[bb];
        for (int off = 32; off; off >>= 1) v += __shfl_down(v, off);
        if (lane == 0) wsum[wv][bb] = v;
    }
    __syncthreads();
    if (tid < 2)
        x2s[tid] = wsum[0][tid] + wsum[1][tid] + wsum[2][tid] + wsum[3][tid];
    __syncthreads();

    // ---- each wave computes 16 prototype distances for both b rows ----
    const float2* xm2_0 = (const float2*)&xm[0][0];
    const float2* xm2_1 = (const float2*)&xm[1][0];
    for (int pi = 0; pi < 16; ++pi) {
        const int p = wv * 16 + pi;
        const float2* pr = (const float2*)(protos + (size_t)p * K_);
        float a0 = 0.f, a1 = 0.f;
        for (int i2 = lane; i2 < K2_; i2 += 64) {
            float2 pv = pr[i2];
            float2 u0 = xm2_0[i2];
            float2 u1 = xm2_1[i2];
            a0 = fmaf(pv.x, u0.x, a0); a0 = fmaf(pv.y, u0.y, a0);
            a1 = fmaf(pv.x, u1.x, a1); a1 = fmaf(pv.y, u1.y, a1);
        }
        const float* spr = sp + (size_t)p * T_;
        float c0 = 0.f, c1 = 0.f;
        for (int t = lane; t < T_; t += 64) {
            float s = spr[t];
            c0 = fmaf(s, mrow[0][t], c0);
            c1 = fmaf(s, mrow[1][t], c1);
        }
        float d0 = fmaf(-2.f, a0, c0);
        float d1 = fmaf(-2.f, a1, c1);
        for (int off = 32; off; off >>= 1) {
            d0 += __shfl_down(d0, off);
            d1 += __shfl_down(d1, off);
        }
        if (lane == 0) {
            dist[0][p] = x2s[0] + d0;
            dist[1][p] = x2s[1] + d1;
        }
    }
    __syncthreads();

    // ---- write distances; per-wave argmin (first-occurrence tie-break) ----
    if (tid < 128) {
        int bb = tid >> 6;
        out[OFF_DIST + (size_t)(b0 + bb) * P_ + lane] = dist[bb][lane];
    }
    if (wv < 2) {
        const int bb = wv;
        float v = dist[bb][lane];
        int idx = lane;
        for (int off = 32; off; off >>= 1) {
            float ov = __shfl_down(v, off);
            int   oi = __shfl_down(idx, off);
            if (ov < v || (ov == v && oi < idx)) { v = ov; idx = oi; }
        }
        if (lane == 0) {
            sel[bb] = idx;
            const int b = b0 + bb;
            out[OFF_IDX + b] = (float)idx;
            out[OFF_LAB + b] = (float)label[b];
        }
    }
    __syncthreads();

    // ---- gather selected prototype row into output_seq ----
#pragma unroll
    for (int bb = 0; bb < 2; ++bb) {
        const float2* src = (const float2*)(protos + (size_t)sel[bb] * K_);
        float2* dst = (float2*)(out + OFF_OUT0 + (size_t)(b0 + bb) * K_);
        for (int i2 = tid; i2 < K2_; i2 += 256) dst[i2] = src[i2];
    }
}

extern "C" void kernel_launch(void* const* d_in, const int* in_sizes, int n_in,
                              void* d_out, int out_size, void* d_ws, size_t ws_size,
                              hipStream_t stream) {
    const float* x      = (const float*)d_in[0];
    const float* mask   = (const float*)d_in[1];
    const int*   label  = (const int*)d_in[2];
    const float* protos = (const float*)d_in[3];
    float* out = (float*)d_out;
    float* sp  = (float*)d_ws;   // P_*T_ floats = 93,440 B

    // pass-through echoes (captured as memcpy nodes, graph-safe)
    hipMemcpyAsync(out + OFF_IN,   x,    (size_t)B_ * K_ * sizeof(float),
                   hipMemcpyDeviceToDevice, stream);
    hipMemcpyAsync(out + OFF_MASK, mask, (size_t)B_ * T_ * sizeof(float),
                   hipMemcpyDeviceToDevice, stream);

    sp_kernel<<<(P_ * T_ + 255) / 256, 256, 0, stream>>>(protos, sp);
    dist_kernel<<<B_ / 2, 256, 0, stream>>>(x, mask, label, protos, sp, out);
}

// Round 2
// 90.601 us; speedup vs baseline: 2.5884x; 2.5884x over previous
//
#include <hip/hip_runtime.h>

#define B_  512
#define T_  365
#define C_  10
#define P_  64
#define K_  3650   // T*C
#define K2_ 1825   // K_/2 as float2
#define KP_ 3712   // padded float count (1856 float2), zero-filled tail

// d_out flat offsets (floats), in reference return order
#define OFF_OUT0 0u          // output_seq [B,T,C]
#define OFF_IN   1868800u    // input_seq  [B,T,C]
#define OFF_DIST 3737600u    // distances  [B,P]
#define OFF_IDX  3770368u    // indices    [B]
#define OFF_LAB  3770880u    // label      [B]
#define OFF_MASK 3771392u    // mask       [B,T]

// One block per 2 batch rows; 1024 threads = 16 waves; wave w owns protos
// [4w, 4w+4). Distance computed in direct masked form:
//   d[b][p] = sum_k (xm[k] - m[k]*proto[p][k])^2,  xm = m*x
// which equals the reference expansion exactly (m binary). Zero-padded LDS
// tail makes out-of-range lanes contribute 0 for ANY proto value, so only
// the proto load index needs clamping.
__global__ __launch_bounds__(1024) void dist_kernel(
    const float* __restrict__ x, const float* __restrict__ mask,
    const int* __restrict__ label, const float* __restrict__ protos,
    float* __restrict__ out)
{
    __shared__ float xm[2][KP_];    // masked x rows, zero-padded
    __shared__ float mexp[2][KP_];  // mask expanded to per-element, zero-padded
    __shared__ float mrow[2][368];  // raw mask rows (staging only)
    __shared__ float dist[2][64];
    __shared__ int   sel[2];

    const int tid  = threadIdx.x;
    const int lane = tid & 63;
    const int wv   = tid >> 6;      // 0..15
    const int b0   = blockIdx.x * 2;

    // ---- stage mask rows (single pass, no loop: T_=365 < 512) ----
    if (tid < T_)                    mrow[0][tid] = mask[(size_t)b0 * T_ + tid];
    {
        int t2 = tid - 512;
        if (t2 >= 0 && t2 < T_)      mrow[1][t2] = mask[(size_t)(b0 + 1) * T_ + t2];
    }
    __syncthreads();

    // ---- build xm / mexp (coalesced x reads; i/10 -> magic-mul) ----
    for (int i = tid; i < KP_; i += 1024) {
#pragma unroll
        for (int bb = 0; bb < 2; ++bb) {
            float m = 0.f, v = 0.f;
            if (i < K_) {
                m = mrow[bb][i / C_];
                v = x[(size_t)(b0 + bb) * K_ + i] * m;
            }
            xm[bb][i]   = v;
            mexp[bb][i] = m;
        }
    }
    __syncthreads();

    // ---- main loop: 4 protos x 2 rows per wave, 29 K-steps ----
    const int p0 = wv * 4;
    const float2* pr[4];
#pragma unroll
    for (int q = 0; q < 4; ++q)
        pr[q] = (const float2*)(protos + (size_t)(p0 + q) * K_);
    const float2* xr0 = (const float2*)&xm[0][0];
    const float2* xr1 = (const float2*)&xm[1][0];
    const float2* mr0 = (const float2*)&mexp[0][0];
    const float2* mr1 = (const float2*)&mexp[1][0];

    float acc0[4] = {0.f, 0.f, 0.f, 0.f};
    float acc1[4] = {0.f, 0.f, 0.f, 0.f};

#pragma unroll 2
    for (int it = 0; it < 29; ++it) {
        const int i2  = it * 64 + lane;           // < 1856, LDS is padded
        const int i2c = i2 < K2_ ? i2 : (K2_ - 1); // clamp proto load only
        float2 pv[4];
#pragma unroll
        for (int q = 0; q < 4; ++q) pv[q] = pr[q][i2c];  // 4 independent L2 loads
        const float2 u0 = xr0[i2], m0 = mr0[i2];
        const float2 u1 = xr1[i2], m1 = mr1[i2];
#pragma unroll
        for (int q = 0; q < 4; ++q) {
            float tx, ty;
            tx = fmaf(-pv[q].x, m0.x, u0.x); acc0[q] = fmaf(tx, tx, acc0[q]);
            ty = fmaf(-pv[q].y, m0.y, u0.y); acc0[q] = fmaf(ty, ty, acc0[q]);
            tx = fmaf(-pv[q].x, m1.x, u1.x); acc1[q] = fmaf(tx, tx, acc1[q]);
            ty = fmaf(-pv[q].y, m1.y, u1.y); acc1[q] = fmaf(ty, ty, acc1[q]);
        }
    }

    // ---- wave reductions, write per-proto distances to LDS ----
#pragma unroll
    for (int q = 0; q < 4; ++q) {
        float v0 = acc0[q], v1 = acc1[q];
        for (int off = 32; off; off >>= 1) {
            v0 += __shfl_down(v0, off);
            v1 += __shfl_down(v1, off);
        }
        if (lane == 0) {
            dist[0][p0 + q] = v0;
            dist[1][p0 + q] = v1;
        }
    }
    __syncthreads();

    // ---- write distances; per-wave argmin (first-occurrence tie-break) ----
    if (tid < 128) {
        int bb = tid >> 6;
        out[OFF_DIST + (size_t)(b0 + bb) * P_ + lane] = dist[bb][lane];
    }
    if (wv < 2) {
        const int bb = wv;
        float v = dist[bb][lane];
        int idx = lane;
        for (int off = 32; off; off >>= 1) {
            float ov = __shfl_down(v, off);
            int   oi = __shfl_down(idx, off);
            if (ov < v || (ov == v && oi < idx)) { v = ov; idx = oi; }
        }
        if (lane == 0) {
            sel[bb] = idx;
            const int b = b0 + bb;
            out[OFF_IDX + b] = (float)idx;
            out[OFF_LAB + b] = (float)label[b];
        }
    }
    __syncthreads();

    // ---- gather selected prototype rows into output_seq ----
#pragma unroll
    for (int bb = 0; bb < 2; ++bb) {
        const float2* src = (const float2*)(protos + (size_t)sel[bb] * K_);
        float2* dst = (float2*)(out + OFF_OUT0 + (size_t)(b0 + bb) * K_);
        for (int i2 = tid; i2 < K2_; i2 += 1024) dst[i2] = src[i2];
    }
}

extern "C" void kernel_launch(void* const* d_in, const int* in_sizes, int n_in,
                              void* d_out, int out_size, void* d_ws, size_t ws_size,
                              hipStream_t stream) {
    const float* x      = (const float*)d_in[0];
    const float* mask   = (const float*)d_in[1];
    const int*   label  = (const int*)d_in[2];
    const float* protos = (const float*)d_in[3];
    float* out = (float*)d_out;

    // pass-through echoes (captured as memcpy nodes, graph-safe)
    hipMemcpyAsync(out + OFF_IN,   x,    (size_t)B_ * K_ * sizeof(float),
                   hipMemcpyDeviceToDevice, stream);
    hipMemcpyAsync(out + OFF_MASK, mask, (size_t)B_ * T_ * sizeof(float),
                   hipMemcpyDeviceToDevice, stream);

    dist_kernel<<<B_ / 2, 1024, 0, stream>>>(x, mask, label, protos, out);
}

// Round 3
// 88.527 us; speedup vs baseline: 2.6491x; 1.0234x over previous
//
#include <hip/hip_runtime.h>

#define B_  512
#define T_  365
#define C_  10
#define P_  64
#define K_  3650   // T*C
#define K2_ 1825   // K_/2 as float2
#define KP_ 3712   // padded float count (1856 float2), zero-filled tail

// d_out flat offsets (floats), in reference return order
#define OFF_OUT0 0u          // output_seq [B,T,C]
#define OFF_IN   1868800u    // input_seq  [B,T,C]
#define OFF_DIST 3737600u    // distances  [B,P]
#define OFF_IDX  3770368u    // indices    [B]
#define OFF_LAB  3770880u    // label      [B]
#define OFF_MASK 3771392u    // mask       [B,T]

// One block per 2 batch rows; 1024 threads = 16 waves; wave w owns protos
// [4w, 4w+4). Distance in direct masked form:
//   d[b][p] = sum_k (xm[k] - m[k]*proto[p][k])^2,  xm = m*x
// (== reference expansion exactly, m binary). Zero-padded LDS tail makes
// out-of-range lanes contribute 0 for ANY proto value, so only the proto
// load index needs clamping. input_seq/mask echoes are fused into staging
// (no graph memcpy nodes — they carried ~25us fixed overhead each).
__global__ __launch_bounds__(1024) void dist_kernel(
    const float* __restrict__ x, const float* __restrict__ mask,
    const int* __restrict__ label, const float* __restrict__ protos,
    float* __restrict__ out)
{
    __shared__ float xm[2][KP_];    // masked x rows, zero-padded
    __shared__ float mexp[2][KP_];  // mask expanded per-element, zero-padded
    __shared__ float mrow[2][368];  // raw mask rows (staging only)
    __shared__ float dist[2][64];
    __shared__ int   sel[2];

    const int tid  = threadIdx.x;
    const int lane = tid & 63;
    const int wv   = tid >> 6;      // 0..15
    const int b0   = blockIdx.x * 2;

    // ---- stage mask rows + fused mask echo ----
    if (tid < T_) {
        float m = mask[(size_t)b0 * T_ + tid];
        mrow[0][tid] = m;
        out[OFF_MASK + (size_t)b0 * T_ + tid] = m;
    }
    {
        int t2 = tid - 512;
        if (t2 >= 0 && t2 < T_) {
            float m = mask[(size_t)(b0 + 1) * T_ + t2];
            mrow[1][t2] = m;
            out[OFF_MASK + (size_t)(b0 + 1) * T_ + t2] = m;
        }
    }
    __syncthreads();

    // ---- build xm / mexp; fused input_seq echo (coalesced) ----
    for (int i = tid; i < KP_; i += 1024) {
#pragma unroll
        for (int bb = 0; bb < 2; ++bb) {
            float m = 0.f, v = 0.f;
            if (i < K_) {
                float xv = x[(size_t)(b0 + bb) * K_ + i];
                out[OFF_IN + (size_t)(b0 + bb) * K_ + i] = xv;
                m = mrow[bb][i / C_];
                v = xv * m;
            }
            xm[bb][i]   = v;
            mexp[bb][i] = m;
        }
    }
    __syncthreads();

    // ---- main loop: 4 protos x 2 rows per wave, 29 K-steps ----
    const int p0 = wv * 4;
    const float2* pr[4];
#pragma unroll
    for (int q = 0; q < 4; ++q)
        pr[q] = (const float2*)(protos + (size_t)(p0 + q) * K_);
    const float2* xr0 = (const float2*)&xm[0][0];
    const float2* xr1 = (const float2*)&xm[1][0];
    const float2* mr0 = (const float2*)&mexp[0][0];
    const float2* mr1 = (const float2*)&mexp[1][0];

    float acc0[4] = {0.f, 0.f, 0.f, 0.f};
    float acc1[4] = {0.f, 0.f, 0.f, 0.f};

#pragma unroll 4
    for (int it = 0; it < 29; ++it) {
        const int i2  = it * 64 + lane;            // < 1856, LDS is padded
        const int i2c = i2 < K2_ ? i2 : (K2_ - 1); // clamp proto load only
        float2 pv[4];
#pragma unroll
        for (int q = 0; q < 4; ++q) pv[q] = pr[q][i2c];  // 4 indep L2 loads
        const float2 u0 = xr0[i2], m0 = mr0[i2];
        const float2 u1 = xr1[i2], m1 = mr1[i2];
#pragma unroll
        for (int q = 0; q < 4; ++q) {
            float tx, ty;
            tx = fmaf(-pv[q].x, m0.x, u0.x); acc0[q] = fmaf(tx, tx, acc0[q]);
            ty = fmaf(-pv[q].y, m0.y, u0.y); acc0[q] = fmaf(ty, ty, acc0[q]);
            tx = fmaf(-pv[q].x, m1.x, u1.x); acc1[q] = fmaf(tx, tx, acc1[q]);
            ty = fmaf(-pv[q].y, m1.y, u1.y); acc1[q] = fmaf(ty, ty, acc1[q]);
        }
    }

    // ---- wave reductions, write per-proto distances to LDS ----
#pragma unroll
    for (int q = 0; q < 4; ++q) {
        float v0 = acc0[q], v1 = acc1[q];
        for (int off = 32; off; off >>= 1) {
            v0 += __shfl_down(v0, off);
            v1 += __shfl_down(v1, off);
        }
        if (lane == 0) {
            dist[0][p0 + q] = v0;
            dist[1][p0 + q] = v1;
        }
    }
    __syncthreads();

    // ---- write distances; per-wave argmin (first-occurrence tie-break) ----
    if (tid < 128) {
        int bb = tid >> 6;
        out[OFF_DIST + (size_t)(b0 + bb) * P_ + lane] = dist[bb][lane];
    }
    if (wv < 2) {
        const int bb = wv;
        float v = dist[bb][lane];
        int idx = lane;
        for (int off = 32; off; off >>= 1) {
            float ov = __shfl_down(v, off);
            int   oi = __shfl_down(idx, off);
            if (ov < v || (ov == v && oi < idx)) { v = ov; idx = oi; }
        }
        if (lane == 0) {
            sel[bb] = idx;
            const int b = b0 + bb;
            out[OFF_IDX + b] = (float)idx;
            out[OFF_LAB + b] = (float)label[b];
        }
    }
    __syncthreads();

    // ---- gather selected prototype rows into output_seq ----
#pragma unroll
    for (int bb = 0; bb < 2; ++bb) {
        const float2* src = (const float2*)(protos + (size_t)sel[bb] * K_);
        float2* dst = (float2*)(out + OFF_OUT0 + (size_t)(b0 + bb) * K_);
        for (int i2 = tid; i2 < K2_; i2 += 1024) dst[i2] = src[i2];
    }
}

extern "C" void kernel_launch(void* const* d_in, const int* in_sizes, int n_in,
                              void* d_out, int out_size, void* d_ws, size_t ws_size,
                              hipStream_t stream) {
    const float* x      = (const float*)d_in[0];
    const float* mask   = (const float*)d_in[1];
    const int*   label  = (const int*)d_in[2];
    const float* protos = (const float*)d_in[3];
    float* out = (float*)d_out;

    dist_kernel<<<B_ / 2, 1024, 0, stream>>>(x, mask, label, protos, out);
}